// Round 1
// baseline (4957.362 us; speedup 1.0000x reference)
//
#include <hip/hip_runtime.h>

#define HH 192
#define WW 192
#define CC 128
#define BB 8
#define HW (HH * WW)          // 36864
#define OC 8
#define NPIX (BB * HW)        // 294912 elements per BN channel

// ---------------------------------------------------------------------------
// K1: fused correlation(11x11, dil 2) + conv3x3(121->8) + bias -> pre-BN y.
// Block: 256 threads = 16x16 corr region; interior 14x14 produces output.
// pi-chunked: 11 corr values/pixel at a time through LDS (stride 13 floats:
// coprime with 32 banks; stride 12 would serialize 8-way).
// ---------------------------------------------------------------------------
__global__ __launch_bounds__(256) void k_corr_conv(
    const float* __restrict__ x0, const float* __restrict__ x1,
    const float* __restrict__ cw, const float* __restrict__ cb,
    float* __restrict__ y)
{
    const int b  = blockIdx.z;
    const int i0 = blockIdx.y * 14;
    const int j0 = blockIdx.x * 14;
    const int li = threadIdx.x >> 4;   // 0..15 region row
    const int lj = threadIdx.x & 15;   // 0..15 region col
    const int gi = i0 + li - 1;
    const int gj = j0 + lj - 1;
    const bool valid    = (gi >= 0) & (gi < HH) & (gj >= 0) & (gj < WW);
    const bool interior = (li >= 1) & (li <= 14) & (lj >= 1) & (lj <= 14)
                        & (gi < HH) & (gj < WW);   // gi,gj >= 0 implied by li,lj >= 1

    __shared__ float corr[16][16][13];

    float yacc[OC];
#pragma unroll
    for (int o = 0; o < OC; ++o) yacc[o] = 0.f;

    const size_t bbase = (size_t)b * CC * HW;
    const float* x0p = x0 + bbase + (size_t)gi * WW + gj;  // only deref'd if valid

    for (int pi = 0; pi < 11; ++pi) {
        float acc[11];
#pragma unroll
        for (int k = 0; k < 11; ++k) acc[k] = 0.f;

        const int r = gi + 2 * pi - 10;
        if (valid && r >= 0 && r < HH) {
            const float* p0 = x0p;
            if (gj >= 10 && gj <= WW - 11) {
                // fast path: whole displacement span in-image
                const float* p1o = x1 + bbase + (size_t)r * WW + (gj - 10);
#pragma unroll 2
                for (int c = 0; c < CC; ++c) {
                    const float a = *p0;
#pragma unroll
                    for (int k = 0; k < 11; ++k)
                        acc[k] = fmaf(a, p1o[2 * k], acc[k]);
                    p0 += HW; p1o += HW;
                }
            } else {
                const float* p1 = x1 + bbase + (size_t)r * WW;
#pragma unroll 2
                for (int c = 0; c < CC; ++c) {
                    const float a = *p0;
#pragma unroll
                    for (int k = 0; k < 11; ++k) {
                        const int col = gj + 2 * k - 10;
                        const float v = (col >= 0 && col < WW) ? p1[col] : 0.f;
                        acc[k] = fmaf(a, v, acc[k]);
                    }
                    p0 += HW; p1 += HW;
                }
            }
        }

        __syncthreads();   // previous pi's conv reads are done
#pragma unroll
        for (int k = 0; k < 11; ++k) corr[li][lj][k] = acc[k];
        __syncthreads();

        if (interior) {
#pragma unroll
            for (int ki = 0; ki < 3; ++ki) {
#pragma unroll
                for (int kj = 0; kj < 3; ++kj) {
                    float cv[11];
#pragma unroll
                    for (int k = 0; k < 11; ++k)
                        cv[k] = corr[li + ki - 1][lj + kj - 1][k];
#pragma unroll
                    for (int o = 0; o < OC; ++o) {
#pragma unroll
                        for (int k = 0; k < 11; ++k) {
                            // uniform index across wave -> scalar (s_load) path
                            const float wv =
                                cw[(((o * 121) + pi * 11 + k) * 3 + ki) * 3 + kj];
                            yacc[o] = fmaf(wv, cv[k], yacc[o]);
                        }
                    }
                }
            }
        }
    }

    if (interior) {
#pragma unroll
        for (int o = 0; o < OC; ++o)
            y[(size_t)(b * OC + o) * HW + (size_t)gi * WW + gj] = yacc[o] + cb[o];
    }
}

// ---------------------------------------------------------------------------
// K2a: per-(b,o) partial sum/sumsq over one HxW image (deterministic, no atomics)
// ---------------------------------------------------------------------------
__global__ __launch_bounds__(256) void k_stats_partial(
    const float* __restrict__ y, float* __restrict__ ws)
{
    const int o = blockIdx.x & 7;
    const int b = blockIdx.x >> 3;
    const float4* p = (const float4*)(y + (size_t)(b * OC + o) * HW);
    float s = 0.f, q = 0.f;
    for (int t = threadIdx.x; t < HW / 4; t += 256) {
        const float4 v = p[t];
        s += v.x + v.y + v.z + v.w;
        q = fmaf(v.x, v.x, q); q = fmaf(v.y, v.y, q);
        q = fmaf(v.z, v.z, q); q = fmaf(v.w, v.w, q);
    }
#pragma unroll
    for (int off = 32; off > 0; off >>= 1) {
        s += __shfl_down(s, off);
        q += __shfl_down(q, off);
    }
    __shared__ float ss[4], sq[4];
    const int lane = threadIdx.x & 63, wv = threadIdx.x >> 6;
    if (lane == 0) { ss[wv] = s; sq[wv] = q; }
    __syncthreads();
    if (threadIdx.x == 0) {
        ws[blockIdx.x]      = ss[0] + ss[1] + ss[2] + ss[3];
        ws[64 + blockIdx.x] = sq[0] + sq[1] + sq[2] + sq[3];
    }
}

// ---------------------------------------------------------------------------
// K2b: finalize BN stats -> scale/shift (biased var, training mode)
// ---------------------------------------------------------------------------
__global__ void k_stats_final(float* __restrict__ ws,
                              const float* __restrict__ gamma,
                              const float* __restrict__ beta)
{
    const int o = threadIdx.x;
    if (o < 8) {
        float S = 0.f, Q = 0.f;
#pragma unroll
        for (int b = 0; b < 8; ++b) {
            S += ws[b * 8 + o];
            Q += ws[64 + b * 8 + o];
        }
        const float invN = 1.f / (float)NPIX;
        const float mean = S * invN;
        const float var  = Q * invN - mean * mean;
        const float sc   = gamma[o] / sqrtf(var + 1e-5f);
        ws[128 + o] = sc;
        ws[136 + o] = beta[o] - mean * sc;
    }
}

// ---------------------------------------------------------------------------
// K3: in-place BN affine + ReLU over d_out, float4
// ---------------------------------------------------------------------------
__global__ __launch_bounds__(256) void k_bn_relu(
    float* __restrict__ y, const float* __restrict__ ws)
{
    const int i = blockIdx.x * 256 + threadIdx.x;     // float4 index, exact grid
    const int o = (i / (HW / 4)) & 7;
    const float sc = ws[128 + o], sh = ws[136 + o];
    float4 v = ((float4*)y)[i];
    v.x = fmaxf(fmaf(v.x, sc, sh), 0.f);
    v.y = fmaxf(fmaf(v.y, sc, sh), 0.f);
    v.z = fmaxf(fmaf(v.z, sc, sh), 0.f);
    v.w = fmaxf(fmaf(v.w, sc, sh), 0.f);
    ((float4*)y)[i] = v;
}

extern "C" void kernel_launch(void* const* d_in, const int* in_sizes, int n_in,
                              void* d_out, int out_size, void* d_ws, size_t ws_size,
                              hipStream_t stream)
{
    const float* x0    = (const float*)d_in[0];
    const float* x1    = (const float*)d_in[1];
    const float* cw    = (const float*)d_in[2];
    const float* cb    = (const float*)d_in[3];
    const float* gamma = (const float*)d_in[4];
    const float* beta  = (const float*)d_in[5];
    float* y  = (float*)d_out;
    float* ws = (float*)d_ws;   // uses 144 floats (576 B)

    dim3 g1(14, 14, 8);                      // 14x14 interior tiles cover 192
    k_corr_conv<<<g1, 256, 0, stream>>>(x0, x1, cw, cb, y);
    k_stats_partial<<<64, 256, 0, stream>>>(y, ws);
    k_stats_final<<<1, 64, 0, stream>>>(ws, gamma, beta);
    k_bn_relu<<<(OC * BB * HW / 4) / 256, 256, 0, stream>>>(y, ws);
}

// Round 2
// 611.744 us; speedup vs baseline: 8.1037x; 8.1037x over previous
//
#include <hip/hip_runtime.h>

#define HH 192
#define WW 192
#define CC 128
#define BB 8
#define HW (HH * WW)          // 36864
#define OC 8
#define NPIX (BB * HW)        // 294912 elements per BN channel

typedef __attribute__((ext_vector_type(8))) short bf16x8;
typedef __attribute__((ext_vector_type(4))) float f32x4;

__device__ __forceinline__ unsigned short f2bf(float f) {
    unsigned int u = __float_as_uint(f);
    u += 0x7fffu + ((u >> 16) & 1u);          // RNE
    return (unsigned short)(u >> 16);
}
__device__ __forceinline__ float bf2f(unsigned short u) {
    return __uint_as_float(((unsigned int)u) << 16);
}

// ---------------------------------------------------------------------------
// T0: fp32 [b][c][h][w] -> bf16 [b][h][w][c] (c-contiguous for MFMA frags)
// grid (h=192, b=8, which=2), 256 thr. LDS stride 130 halfwords: phase-1
// writes step banks by 1 (65*w), phase-2 reads are word-consecutive.
// ---------------------------------------------------------------------------
__global__ __launch_bounds__(256) void k_transpose(
    const float* __restrict__ x0, const float* __restrict__ x1,
    unsigned short* __restrict__ ws)
{
    const int h = blockIdx.x, b = blockIdx.y, t = blockIdx.z;
    const float* src = t ? x1 : x0;
    unsigned short* dst = ws + (size_t)t * ((size_t)BB * HH * WW * CC);
    __shared__ unsigned short lds[WW * 130];

    for (int idx = threadIdx.x; idx < CC * WW; idx += 256) {
        const int w = idx % WW, c = idx / WW;     // lanes: consecutive w -> coalesced
        const float v = src[((size_t)(b * CC + c) * HH + h) * WW + w];
        lds[w * 130 + c] = f2bf(v);
    }
    __syncthreads();
    unsigned int* dw = (unsigned int*)(dst + (size_t)(b * HH + h) * WW * CC);
    for (int idx = threadIdx.x; idx < WW * (CC / 2); idx += 256) {
        const int w = idx / (CC / 2), cp = idx % (CC / 2);  // lanes: consecutive cp
        const unsigned int lo = lds[w * 130 + 2 * cp];
        const unsigned int hi = lds[w * 130 + 2 * cp + 1];
        dw[w * (CC / 2) + cp] = lo | (hi << 16);
    }
}

// ---------------------------------------------------------------------------
// K1-MFMA: fused band-GEMM correlation + conv3x3(121->8) + bias.
// Block = (b, strip of 6 output rows): corr rows 8 (1-halo each side).
// Per pi: 8 rows x 2 parities x 6 u-tiles x 2 v-tiles MFMA chains (K=128 as
// 4x K=32), band-extract into corr LDS (bf16, [8][194][11], stride 11 words
// is coprime with 32 banks), then VALU conv accumulates 3 px/thread.
// ---------------------------------------------------------------------------
__global__ __launch_bounds__(384, 3) void k_corr_mfma_conv(
    const unsigned short* __restrict__ x0t, const unsigned short* __restrict__ x1t,
    const float* __restrict__ cw, const float* __restrict__ cb,
    float* __restrict__ y)
{
    const int b    = blockIdx.y;
    const int i0   = blockIdx.x * 6;
    const int tid  = threadIdx.x;
    const int wave = tid >> 6, lane = tid & 63;
    const int ln15 = lane & 15, kg = lane >> 4;

    __shared__ unsigned short corr[8][194][11];   // jj = col+1 (zero-pad cols 0,193)

    if (tid < 176) {                               // zero the pad columns once
        const int ir = tid / 22, rem = tid % 22;
        const int pj = rem % 11, jj = (rem < 11) ? 0 : 193;
        corr[ir][jj][pj] = 0;
    }

    float yacc[3][OC];
#pragma unroll
    for (int k = 0; k < 3; ++k)
#pragma unroll
        for (int o = 0; o < OC; ++o) yacc[k][o] = 0.f;

    const int jt  = tid % 192;      // conv: this thread's column
    const int irb = tid / 192;      // conv: 0/1; rows irb, irb+2, irb+4

    const bf16x8 zf = {0,0,0,0,0,0,0,0};

    for (int pi = 0; pi < 11; ++pi) {
        __syncthreads();            // conv(pi-1) finished reading corr LDS

        // ---------------- MFMA band-GEMM phase ----------------
        for (int g = wave; g < 96; g += 6) {
            const int ir  = g / 12, rem = g % 12;
            const int par = rem / 6, ut = rem % 6;
            const int u0  = ut * 16;
            const int i   = i0 - 1 + ir;
            const bool iv = (i >= 0) && (i < HH);
            const int r   = i + 2 * pi - 10;
            const bool rv = iv && (r >= 0) && (r < HH);
            const int icl = iv ? i : 0;
            const int rcl = rv ? r : 0;

            // A fragments: row u = u0+ln15, k = c (kg*8 + 0..7), 4 K-chunks
            const unsigned short* pa =
                x0t + ((size_t)((b * HH + icl) * WW + (2 * (u0 + ln15) + par)) * CC + kg * 8);
            bf16x8 a0, a1, a2, a3;
            if (iv) {
                a0 = *(const bf16x8*)(pa);
                a1 = *(const bf16x8*)(pa + 32);
                a2 = *(const bf16x8*)(pa + 64);
                a3 = *(const bf16x8*)(pa + 96);
            } else { a0 = a1 = a2 = a3 = zf; }

#pragma unroll
            for (int vt = 0; vt < 2; ++vt) {
                const int v0 = u0 - 8 + vt * 16;
                const int v  = v0 + ln15;
                const bool vv = rv && (v >= 0) && (v < 96);
                const int vcl = (v < 0) ? 0 : (v > 95 ? 95 : v);
                const unsigned short* pb =
                    x1t + ((size_t)((b * HH + rcl) * WW + (2 * vcl + par)) * CC + kg * 8);
                bf16x8 b0 = *(const bf16x8*)(pb);
                bf16x8 b1 = *(const bf16x8*)(pb + 32);
                bf16x8 b2 = *(const bf16x8*)(pb + 64);
                bf16x8 b3 = *(const bf16x8*)(pb + 96);
                if (!vv) { b0 = zf; b1 = zf; b2 = zf; b3 = zf; }

                f32x4 c = {0.f, 0.f, 0.f, 0.f};
                c = __builtin_amdgcn_mfma_f32_16x16x32_bf16(a0, b0, c, 0, 0, 0);
                c = __builtin_amdgcn_mfma_f32_16x16x32_bf16(a1, b1, c, 0, 0, 0);
                c = __builtin_amdgcn_mfma_f32_16x16x32_bf16(a2, b2, c, 0, 0, 0);
                c = __builtin_amdgcn_mfma_f32_16x16x32_bf16(a3, b3, c, 0, 0, 0);

                // band extract: C lane holds col n=ln15 (v), rows m=kg*4+reg (u)
#pragma unroll
                for (int reg = 0; reg < 4; ++reg) {
                    const int u  = u0 + kg * 4 + reg;
                    const int pj = v0 + ln15 - u + 5;
                    if (pj >= 0 && pj < 11)
                        corr[ir][2 * u + par + 1][pj] = f2bf(c[reg]);
                }
            }
        }
        __syncthreads();            // corr slice visible

        // ---------------- conv(3x3, 121->8) VALU phase ----------------
        for (int ki = 0; ki < 3; ++ki) {
            for (int kj = 0; kj < 3; ++kj) {
                float cv[3][11];
#pragma unroll
                for (int k = 0; k < 3; ++k) {
                    const unsigned short* cp = &corr[irb + 2 * k + ki][jt + kj][0];
#pragma unroll
                    for (int pj = 0; pj < 11; ++pj) cv[k][pj] = bf2f(cp[pj]);
                }
#pragma unroll
                for (int o = 0; o < OC; ++o) {
                    float y0 = yacc[0][o], y1 = yacc[1][o], y2 = yacc[2][o];
#pragma unroll
                    for (int pj = 0; pj < 11; ++pj) {
                        const float wv =                    // wave-uniform -> s_load
                            cw[(((o * 121) + pi * 11 + pj) * 3 + ki) * 3 + kj];
                        y0 = fmaf(wv, cv[0][pj], y0);
                        y1 = fmaf(wv, cv[1][pj], y1);
                        y2 = fmaf(wv, cv[2][pj], y2);
                    }
                    yacc[0][o] = y0; yacc[1][o] = y1; yacc[2][o] = y2;
                }
            }
        }
    }

#pragma unroll
    for (int k = 0; k < 3; ++k) {
        const int irow = i0 + irb + 2 * k;
#pragma unroll
        for (int o = 0; o < OC; ++o)
            y[((size_t)(b * OC + o) * HH + irow) * WW + jt] = yacc[k][o] + cb[o];
    }
}

// ---------------------------------------------------------------------------
// Fallback K1 (round-1 verified): fp32 scalar path, used only if ws too small
// ---------------------------------------------------------------------------
__global__ __launch_bounds__(256) void k_corr_conv(
    const float* __restrict__ x0, const float* __restrict__ x1,
    const float* __restrict__ cw, const float* __restrict__ cb,
    float* __restrict__ y)
{
    const int b  = blockIdx.z;
    const int i0 = blockIdx.y * 14;
    const int j0 = blockIdx.x * 14;
    const int li = threadIdx.x >> 4;
    const int lj = threadIdx.x & 15;
    const int gi = i0 + li - 1;
    const int gj = j0 + lj - 1;
    const bool valid    = (gi >= 0) & (gi < HH) & (gj >= 0) & (gj < WW);
    const bool interior = (li >= 1) & (li <= 14) & (lj >= 1) & (lj <= 14)
                        & (gi < HH) & (gj < WW);

    __shared__ float corr[16][16][13];

    float yacc[OC];
#pragma unroll
    for (int o = 0; o < OC; ++o) yacc[o] = 0.f;

    const size_t bbase = (size_t)b * CC * HW;
    const float* x0p = x0 + bbase + (size_t)gi * WW + gj;

    for (int pi = 0; pi < 11; ++pi) {
        float acc[11];
#pragma unroll
        for (int k = 0; k < 11; ++k) acc[k] = 0.f;

        const int r = gi + 2 * pi - 10;
        if (valid && r >= 0 && r < HH) {
            const float* p0 = x0p;
            if (gj >= 10 && gj <= WW - 11) {
                const float* p1o = x1 + bbase + (size_t)r * WW + (gj - 10);
#pragma unroll 2
                for (int c = 0; c < CC; ++c) {
                    const float a = *p0;
#pragma unroll
                    for (int k = 0; k < 11; ++k)
                        acc[k] = fmaf(a, p1o[2 * k], acc[k]);
                    p0 += HW; p1o += HW;
                }
            } else {
                const float* p1 = x1 + bbase + (size_t)r * WW;
#pragma unroll 2
                for (int c = 0; c < CC; ++c) {
                    const float a = *p0;
#pragma unroll
                    for (int k = 0; k < 11; ++k) {
                        const int col = gj + 2 * k - 10;
                        const float v = (col >= 0 && col < WW) ? p1[col] : 0.f;
                        acc[k] = fmaf(a, v, acc[k]);
                    }
                    p0 += HW; p1 += HW;
                }
            }
        }

        __syncthreads();
#pragma unroll
        for (int k = 0; k < 11; ++k) corr[li][lj][k] = acc[k];
        __syncthreads();

        if (interior) {
#pragma unroll
            for (int ki = 0; ki < 3; ++ki) {
#pragma unroll
                for (int kj = 0; kj < 3; ++kj) {
                    float cv[11];
#pragma unroll
                    for (int k = 0; k < 11; ++k)
                        cv[k] = corr[li + ki - 1][lj + kj - 1][k];
#pragma unroll
                    for (int o = 0; o < OC; ++o) {
#pragma unroll
                        for (int k = 0; k < 11; ++k) {
                            const float wv =
                                cw[(((o * 121) + pi * 11 + k) * 3 + ki) * 3 + kj];
                            yacc[o] = fmaf(wv, cv[k], yacc[o]);
                        }
                    }
                }
            }
        }
    }

    if (interior) {
#pragma unroll
        for (int o = 0; o < OC; ++o)
            y[(size_t)(b * OC + o) * HW + (size_t)gi * WW + gj] = yacc[o] + cb[o];
    }
}

// ---------------------------------------------------------------------------
// BN stats + apply (unchanged from round 1)
// ---------------------------------------------------------------------------
__global__ __launch_bounds__(256) void k_stats_partial(
    const float* __restrict__ y, float* __restrict__ ws)
{
    const int o = blockIdx.x & 7;
    const int b = blockIdx.x >> 3;
    const float4* p = (const float4*)(y + (size_t)(b * OC + o) * HW);
    float s = 0.f, q = 0.f;
    for (int t = threadIdx.x; t < HW / 4; t += 256) {
        const float4 v = p[t];
        s += v.x + v.y + v.z + v.w;
        q = fmaf(v.x, v.x, q); q = fmaf(v.y, v.y, q);
        q = fmaf(v.z, v.z, q); q = fmaf(v.w, v.w, q);
    }
#pragma unroll
    for (int off = 32; off > 0; off >>= 1) {
        s += __shfl_down(s, off);
        q += __shfl_down(q, off);
    }
    __shared__ float ss[4], sq[4];
    const int lane = threadIdx.x & 63, wv = threadIdx.x >> 6;
    if (lane == 0) { ss[wv] = s; sq[wv] = q; }
    __syncthreads();
    if (threadIdx.x == 0) {
        ws[blockIdx.x]      = ss[0] + ss[1] + ss[2] + ss[3];
        ws[64 + blockIdx.x] = sq[0] + sq[1] + sq[2] + sq[3];
    }
}

__global__ void k_stats_final(float* __restrict__ ws,
                              const float* __restrict__ gamma,
                              const float* __restrict__ beta)
{
    const int o = threadIdx.x;
    if (o < 8) {
        float S = 0.f, Q = 0.f;
#pragma unroll
        for (int b = 0; b < 8; ++b) {
            S += ws[b * 8 + o];
            Q += ws[64 + b * 8 + o];
        }
        const float invN = 1.f / (float)NPIX;
        const float mean = S * invN;
        const float var  = Q * invN - mean * mean;
        const float sc   = gamma[o] / sqrtf(var + 1e-5f);
        ws[128 + o] = sc;
        ws[136 + o] = beta[o] - mean * sc;
    }
}

__global__ __launch_bounds__(256) void k_bn_relu(
    float* __restrict__ y, const float* __restrict__ ws)
{
    const int i = blockIdx.x * 256 + threadIdx.x;
    const int o = (i / (HW / 4)) & 7;
    const float sc = ws[128 + o], sh = ws[136 + o];
    float4 v = ((float4*)y)[i];
    v.x = fmaxf(fmaf(v.x, sc, sh), 0.f);
    v.y = fmaxf(fmaf(v.y, sc, sh), 0.f);
    v.z = fmaxf(fmaf(v.z, sc, sh), 0.f);
    v.w = fmaxf(fmaf(v.w, sc, sh), 0.f);
    ((float4*)y)[i] = v;
}

extern "C" void kernel_launch(void* const* d_in, const int* in_sizes, int n_in,
                              void* d_out, int out_size, void* d_ws, size_t ws_size,
                              hipStream_t stream)
{
    const float* x0    = (const float*)d_in[0];
    const float* x1    = (const float*)d_in[1];
    const float* cw    = (const float*)d_in[2];
    const float* cb    = (const float*)d_in[3];
    const float* gamma = (const float*)d_in[4];
    const float* beta  = (const float*)d_in[5];
    float* y  = (float*)d_out;
    float* ws = (float*)d_ws;

    const size_t need = (size_t)2 * BB * HH * WW * CC * sizeof(unsigned short); // 151 MB

    if (ws_size >= need) {
        unsigned short* x0t = (unsigned short*)d_ws;
        unsigned short* x1t = x0t + (size_t)BB * HH * WW * CC;
        k_transpose<<<dim3(HH, BB, 2), 256, 0, stream>>>(x0, x1, (unsigned short*)d_ws);
        k_corr_mfma_conv<<<dim3(32, BB), 384, 0, stream>>>(x0t, x1t, cw, cb, y);
    } else {
        dim3 g1(14, 14, 8);
        k_corr_conv<<<g1, 256, 0, stream>>>(x0, x1, cw, cb, y);
    }
    k_stats_partial<<<64, 256, 0, stream>>>(y, ws);
    k_stats_final<<<1, 64, 0, stream>>>(ws, gamma, beta);
    k_bn_relu<<<(OC * BB * HW / 4) / 256, 256, 0, stream>>>(y, ws);
}